// Round 1
// baseline (650.874 us; speedup 1.0000x reference)
//
#include <hip/hip_runtime.h>
#include <hip/hip_bf16.h>

#define C 64  // C_IN == C_OUT == 64
#define KORD 3

// --- Kernel 1: degree accumulation: deg[row[e]] += ew[e] ---
__global__ void deg_kernel(const int* __restrict__ row,
                           const float* __restrict__ ew,
                           float* __restrict__ deg, int E) {
    int e = blockIdx.x * blockDim.x + threadIdx.x;
    if (e < E) atomicAdd(&deg[row[e]], ew[e]);
}

// --- Kernel 2: deg -> deg_inv_sqrt (in place) ---
__global__ void dis_kernel(float* __restrict__ deg, int N) {
    int i = blockIdx.x * blockDim.x + threadIdx.x;
    if (i < N) {
        float d = deg[i];
        deg[i] = (d > 0.0f) ? rsqrtf(d) : 0.0f;
    }
}

// --- Kernel 3: normalized Laplacian edge weights ---
__global__ void w_kernel(const int* __restrict__ row,
                         const int* __restrict__ col,
                         const float* __restrict__ ew,
                         const float* __restrict__ dis,
                         float* __restrict__ w, int E) {
    int e = blockIdx.x * blockDim.x + threadIdx.x;
    if (e < E) {
        w[e] = -dis[row[e]] * ew[e] * dis[col[e]];
    }
}

// --- Kernel 4: SpMM  out[row[e], c] += w[e] * h[col[e], c]
// one wave (64 lanes) per edge; lane = channel -> fully coalesced
__global__ void spmm_kernel(const int* __restrict__ row,
                            const int* __restrict__ col,
                            const float* __restrict__ w,
                            const float* __restrict__ h,
                            float* __restrict__ out, int E) {
    long long t = (long long)blockIdx.x * blockDim.x + threadIdx.x;
    int e = (int)(t >> 6);
    int c = (int)(t & 63);
    if (e < E) {
        float we = w[e];
        int r = row[e];
        int cl = col[e];
        atomicAdd(&out[(long long)r * C + c], we * h[(long long)cl * C + c]);
    }
}

// --- Kernel 5: fused dense epilogue
// out[i,:] = relu( x[i]@W0 + T1[i]@W1 + (2*P[i]-x[i])@W2 + b )
__global__ __launch_bounds__(256) void final_kernel(
        const float* __restrict__ x,
        const float* __restrict__ T1,
        const float* __restrict__ P,
        const float* __restrict__ W,   // [3,64,64] row-major
        const float* __restrict__ b,
        float* __restrict__ out, int N) {
    __shared__ float sW[KORD * C * C];  // 48 KiB
    for (int i = threadIdx.x; i < KORD * C * C; i += blockDim.x) sW[i] = W[i];
    __syncthreads();

    int c = threadIdx.x & 63;          // output channel
    int local = threadIdx.x >> 6;      // node within block (0..3)
    int node = blockIdx.x * 4 + local;
    if (node >= N) return;

    const float* w0 = sW;
    const float* w1 = sW + C * C;
    const float* w2 = sW + 2 * C * C;

    const float* xr  = x  + (long long)node * C;
    const float* t1r = T1 + (long long)node * C;
    const float* pr  = P  + (long long)node * C;

    float acc = b[c];
#pragma unroll 8
    for (int k = 0; k < C; k++) {
        float t0 = xr[k];
        float t1 = t1r[k];
        float t2 = 2.0f * pr[k] - t0;
        acc = fmaf(t0, w0[k * C + c], acc);
        acc = fmaf(t1, w1[k * C + c], acc);
        acc = fmaf(t2, w2[k * C + c], acc);
    }
    out[(long long)node * C + c] = fmaxf(acc, 0.0f);
}

extern "C" void kernel_launch(void* const* d_in, const int* in_sizes, int n_in,
                              void* d_out, int out_size, void* d_ws, size_t ws_size,
                              hipStream_t stream) {
    const float* x  = (const float*)d_in[0];
    const int*   ei = (const int*)d_in[1];
    const float* ew = (const float*)d_in[2];
    const float* W  = (const float*)d_in[3];
    const float* b  = (const float*)d_in[4];
    float* out = (float*)d_out;

    const int N = in_sizes[0] / C;
    const int E = in_sizes[2];
    const int* row = ei;        // edge_index[0]
    const int* col = ei + E;    // edge_index[1]

    // workspace layout (floats):
    //   dis : N          (also used as deg accumulator)
    //   w   : E
    //   T1  : N*C
    //   P   : N*C
    char* ws = (char*)d_ws;
    float* dis = (float*)ws;                       size_t off = (size_t)N * 4;
    off = (off + 255) & ~(size_t)255;
    float* wgt = (float*)(ws + off);               off += (size_t)E * 4;
    off = (off + 255) & ~(size_t)255;
    float* T1  = (float*)(ws + off);               off += (size_t)N * C * 4;
    off = (off + 255) & ~(size_t)255;
    float* P   = (float*)(ws + off);

    // zero accumulators (ws is poisoned before every call)
    hipMemsetAsync(dis, 0, (size_t)N * 4, stream);
    hipMemsetAsync(T1,  0, (size_t)N * C * 4, stream);
    hipMemsetAsync(P,   0, (size_t)N * C * 4, stream);

    const int B = 256;
    deg_kernel<<<(E + B - 1) / B, B, 0, stream>>>(row, ew, dis, E);
    dis_kernel<<<(N + B - 1) / B, B, 0, stream>>>(dis, N);
    w_kernel<<<(E + B - 1) / B, B, 0, stream>>>(row, col, ew, dis, wgt, E);

    // T1 = L_hat @ x
    long long spmm_threads = (long long)E * 64;
    int spmm_blocks = (int)((spmm_threads + B - 1) / B);
    spmm_kernel<<<spmm_blocks, B, 0, stream>>>(row, col, wgt, x, T1, E);
    // P = L_hat @ T1
    spmm_kernel<<<spmm_blocks, B, 0, stream>>>(row, col, wgt, T1, P, E);

    // fused dense epilogue
    final_kernel<<<(N + 3) / 4, B, 0, stream>>>(x, T1, P, W, b, out, N);
}

// Round 2
// 424.902 us; speedup vs baseline: 1.5318x; 1.5318x over previous
//
#include <hip/hip_runtime.h>
#include <hip/hip_bf16.h>

#define C 64  // C_IN == C_OUT == 64

// --- Kernel 1: fused degree + count histogram ---
__global__ void deg_hist_kernel(const int* __restrict__ row,
                                const float* __restrict__ ew,
                                float* __restrict__ deg,
                                int* __restrict__ cnt, int E) {
    int e = blockIdx.x * blockDim.x + threadIdx.x;
    if (e < E) {
        int r = row[e];
        atomicAdd(&deg[r], ew[e]);
        atomicAdd(&cnt[r], 1);
    }
}

// --- Kernel 2: deg -> deg_inv_sqrt (in place) ---
__global__ void dis_kernel(float* __restrict__ deg, int N) {
    int i = blockIdx.x * blockDim.x + threadIdx.x;
    if (i < N) {
        float d = deg[i];
        deg[i] = (d > 0.0f) ? rsqrtf(d) : 0.0f;
    }
}

// --- Kernel 3: single-block exclusive scan cnt[N] -> rowptr[N+1]; zeros cnt ---
__global__ __launch_bounds__(1024) void scan_kernel(int* __restrict__ cnt,
                                                    int* __restrict__ rowptr,
                                                    int N) {
    __shared__ int part[1024];
    int t = threadIdx.x;
    int per = (N + 1023) / 1024;
    int beg = t * per;
    int end = beg + per; if (end > N) end = N;
    int s = 0;
    for (int i = beg; i < end; i++) s += cnt[i];
    part[t] = s;
    __syncthreads();
    // inclusive Hillis-Steele scan over 1024 partials
    for (int off = 1; off < 1024; off <<= 1) {
        int v = (t >= off) ? part[t - off] : 0;
        __syncthreads();
        part[t] += v;
        __syncthreads();
    }
    int run = (t == 0) ? 0 : part[t - 1];  // exclusive prefix of this chunk
    for (int i = beg; i < end; i++) {
        int c = cnt[i];
        rowptr[i] = run;
        run += c;
        cnt[i] = 0;  // reset for use as fill counter in scatter
    }
    if (t == 1023) rowptr[N] = part[1023];
}

// --- Kernel 4: scatter edges into CSR order, fusing normalized weight ---
// ewc[pos] = { w_e, bitcast(col_e) }
__global__ void scatter_kernel(const int* __restrict__ row,
                               const int* __restrict__ col,
                               const float* __restrict__ ew,
                               const float* __restrict__ dis,
                               const int* __restrict__ rowptr,
                               int* __restrict__ fill,
                               float2* __restrict__ ewc, int E) {
    int e = blockIdx.x * blockDim.x + threadIdx.x;
    if (e < E) {
        int r = row[e];
        int c = col[e];
        float wv = -dis[r] * ew[e] * dis[c];
        int pos = rowptr[r] + atomicAdd(&fill[r], 1);
        ewc[pos] = make_float2(wv, __int_as_float(c));
    }
}

// --- Kernel 5: atomic-free CSR SpMM: one wave per row, lane = channel ---
__global__ __launch_bounds__(256) void spmm_csr_kernel(
        const int* __restrict__ rowptr,
        const float2* __restrict__ ewc,
        const float* __restrict__ h,
        float* __restrict__ out, int N) {
    int wid = (blockIdx.x * blockDim.x + threadIdx.x) >> 6;  // row id
    int lane = threadIdx.x & 63;
    if (wid >= N) return;
    int beg = rowptr[wid];
    int end = rowptr[wid + 1];
    float acc0 = 0.0f, acc1 = 0.0f;
    int p = beg;
    for (; p + 1 < end; p += 2) {
        float2 e0 = ewc[p];
        float2 e1 = ewc[p + 1];
        int c0 = __float_as_int(e0.y);
        int c1 = __float_as_int(e1.y);
        acc0 = fmaf(e0.x, h[c0 * C + lane], acc0);
        acc1 = fmaf(e1.x, h[c1 * C + lane], acc1);
    }
    if (p < end) {
        float2 e0 = ewc[p];
        int c0 = __float_as_int(e0.y);
        acc0 = fmaf(e0.x, h[c0 * C + lane], acc0);
    }
    out[wid * C + lane] = acc0 + acc1;
}

// --- Kernel 6: fused dense epilogue as register-tiled GEMM ---
// out = relu([x | T1 | 2P-x] @ Wcat + b), Wcat = [192][64] (W row-major)
// block: 64 nodes x 64 cols, 256 threads (16x16), 4x4 micro-tile each,
// K staged in 12 slices of 16.
__global__ __launch_bounds__(256) void final_gemm_kernel(
        const float* __restrict__ x,
        const float* __restrict__ T1,
        const float* __restrict__ P,
        const float* __restrict__ W,   // [192][64] row-major
        const float* __restrict__ b,
        float* __restrict__ out, int N) {
    __shared__ float As[16][64];  // [k][node]
    __shared__ float Ws[16][64];  // [k][col]

    int t  = threadIdx.x;
    int tx = t & 15;         // col group: cols tx*4..+3
    int ty = t >> 4;         // row group: nodes ty*4..+3
    int n0 = blockIdx.x * 64;

    // staging coords
    int sn = t >> 2;          // node 0..63
    int skb = (t & 3) * 4;    // k offset within slice (0,4,8,12)

    float acc[4][4];
#pragma unroll
    for (int i = 0; i < 4; i++)
#pragma unroll
        for (int j = 0; j < 4; j++) acc[i][j] = 0.0f;

#pragma unroll 1
    for (int s = 0; s < 12; s++) {
        // load W slice: contiguous 1024 floats
        float4 wv = *(const float4*)(W + s * 1024 + t * 4);
        // load A slice element(s)
        int nn = n0 + sn;
        float4 av = make_float4(0.f, 0.f, 0.f, 0.f);
        if (nn < N) {
            if (s < 4) {
                av = *(const float4*)(x + (size_t)nn * C + s * 16 + skb);
            } else if (s < 8) {
                av = *(const float4*)(T1 + (size_t)nn * C + (s - 4) * 16 + skb);
            } else {
                float4 pv = *(const float4*)(P + (size_t)nn * C + (s - 8) * 16 + skb);
                float4 xv = *(const float4*)(x + (size_t)nn * C + (s - 8) * 16 + skb);
                av = make_float4(2.0f * pv.x - xv.x, 2.0f * pv.y - xv.y,
                                 2.0f * pv.z - xv.z, 2.0f * pv.w - xv.w);
            }
        }
        __syncthreads();  // protect previous iter's reads
        // Ws: thread t covers rows (t*4)/64 .. : write as [k][c]
        {
            int wk = (t * 4) >> 6;        // k row 0..15
            int wc = (t * 4) & 63;        // col
            *(float4*)&Ws[wk][wc] = wv;
        }
        As[skb + 0][sn] = av.x;
        As[skb + 1][sn] = av.y;
        As[skb + 2][sn] = av.z;
        As[skb + 3][sn] = av.w;
        __syncthreads();

#pragma unroll
        for (int kk = 0; kk < 16; kk++) {
            float4 a4 = *(const float4*)&As[kk][ty * 4];
            float4 w4 = *(const float4*)&Ws[kk][tx * 4];
            float ar[4] = {a4.x, a4.y, a4.z, a4.w};
            float wr[4] = {w4.x, w4.y, w4.z, w4.w};
#pragma unroll
            for (int i = 0; i < 4; i++)
#pragma unroll
                for (int j = 0; j < 4; j++)
                    acc[i][j] = fmaf(ar[i], wr[j], acc[i][j]);
        }
    }

    // epilogue: bias + relu, float4 stores
    float4 bv = *(const float4*)(b + tx * 4);
    float br[4] = {bv.x, bv.y, bv.z, bv.w};
#pragma unroll
    for (int i = 0; i < 4; i++) {
        int node = n0 + ty * 4 + i;
        if (node < N) {
            float4 o;
            o.x = fmaxf(acc[i][0] + br[0], 0.0f);
            o.y = fmaxf(acc[i][1] + br[1], 0.0f);
            o.z = fmaxf(acc[i][2] + br[2], 0.0f);
            o.w = fmaxf(acc[i][3] + br[3], 0.0f);
            *(float4*)(out + (size_t)node * C + tx * 4) = o;
        }
    }
}

extern "C" void kernel_launch(void* const* d_in, const int* in_sizes, int n_in,
                              void* d_out, int out_size, void* d_ws, size_t ws_size,
                              hipStream_t stream) {
    const float* x  = (const float*)d_in[0];
    const int*   ei = (const int*)d_in[1];
    const float* ew = (const float*)d_in[2];
    const float* W  = (const float*)d_in[3];
    const float* b  = (const float*)d_in[4];
    float* out = (float*)d_out;

    const int N = in_sizes[0] / C;
    const int E = in_sizes[2];
    const int* row = ei;        // edge_index[0]
    const int* col = ei + E;    // edge_index[1]

    // workspace layout
    char* ws = (char*)d_ws;
    size_t off = 0;
    auto alloc = [&](size_t bytes) {
        void* p = ws + off;
        off = (off + bytes + 255) & ~(size_t)255;
        return p;
    };
    float*  dis    = (float*)alloc((size_t)N * 4);        // deg, then deg_inv_sqrt
    int*    cnt    = (int*)alloc((size_t)N * 4);          // histogram, then fill
    int*    rowptr = (int*)alloc((size_t)(N + 1) * 4);
    float2* ewc    = (float2*)alloc((size_t)E * 8);       // CSR (w, col)
    float*  T1     = (float*)alloc((size_t)N * C * 4);
    float*  P      = (float*)alloc((size_t)N * C * 4);

    hipMemsetAsync(dis, 0, (size_t)N * 4, stream);
    hipMemsetAsync(cnt, 0, (size_t)N * 4, stream);

    const int B = 256;
    deg_hist_kernel<<<(E + B - 1) / B, B, 0, stream>>>(row, ew, dis, cnt, E);
    dis_kernel<<<(N + B - 1) / B, B, 0, stream>>>(dis, N);
    scan_kernel<<<1, 1024, 0, stream>>>(cnt, rowptr, N);
    scatter_kernel<<<(E + B - 1) / B, B, 0, stream>>>(row, col, ew, dis, rowptr,
                                                      cnt, ewc, E);

    int spmm_blocks = (int)(((long long)N * 64 + B - 1) / B);
    spmm_csr_kernel<<<spmm_blocks, B, 0, stream>>>(rowptr, ewc, x, T1, N);
    spmm_csr_kernel<<<spmm_blocks, B, 0, stream>>>(rowptr, ewc, T1, P, N);

    final_gemm_kernel<<<(N + 63) / 64, B, 0, stream>>>(x, T1, P, W, b, out, N);
}

// Round 3
// 295.133 us; speedup vs baseline: 2.2054x; 1.4397x over previous
//
#include <hip/hip_runtime.h>
#include <hip/hip_bf16.h>

#define C 64  // C_IN == C_OUT == 64

// --- Kernel 1: fused degree + count histogram ---
__global__ void deg_hist_kernel(const int* __restrict__ row,
                                const float* __restrict__ ew,
                                float* __restrict__ deg,
                                int* __restrict__ cnt, int E) {
    int e = blockIdx.x * blockDim.x + threadIdx.x;
    if (e < E) {
        int r = row[e];
        atomicAdd(&deg[r], ew[e]);
        atomicAdd(&cnt[r], 1);
    }
}

// --- Kernel 2: deg -> deg_inv_sqrt (in place) ---
__global__ void dis_kernel(float* __restrict__ deg, int N) {
    int i = blockIdx.x * blockDim.x + threadIdx.x;
    if (i < N) {
        float d = deg[i];
        deg[i] = (d > 0.0f) ? rsqrtf(d) : 0.0f;
    }
}

// --- Scan phase A: per-block sums of cnt (256 elems/block) ---
__global__ __launch_bounds__(256) void scanA_kernel(const int* __restrict__ cnt,
                                                    int* __restrict__ bsum, int N) {
    __shared__ int s[256];
    int t = threadIdx.x;
    int i = blockIdx.x * 256 + t;
    int v = (i < N) ? cnt[i] : 0;
    s[t] = v;
    __syncthreads();
    for (int off = 128; off > 0; off >>= 1) {
        if (t < off) s[t] += s[t + off];
        __syncthreads();
    }
    if (t == 0) bsum[blockIdx.x] = s[0];
}

// --- Scan phase B: exclusive scan of G (<=256) block sums; writes rowptr[N] ---
__global__ __launch_bounds__(256) void scanB_kernel(int* __restrict__ bsum,
                                                    int* __restrict__ rowptr,
                                                    int G, int N) {
    __shared__ int s[256];
    int t = threadIdx.x;
    int v = (t < G) ? bsum[t] : 0;
    s[t] = v;
    __syncthreads();
    for (int off = 1; off < 256; off <<= 1) {
        int u = (t >= off) ? s[t - off] : 0;
        __syncthreads();
        s[t] += u;
        __syncthreads();
    }
    if (t < G) bsum[t] = s[t] - v;          // exclusive block prefix
    if (t == 255) rowptr[N] = s[255];       // total edge count
}

// --- Scan phase C: per-block exclusive scan + block offset; zeros cnt ---
__global__ __launch_bounds__(256) void scanC_kernel(int* __restrict__ cnt,
                                                    const int* __restrict__ bsum,
                                                    int* __restrict__ rowptr, int N) {
    __shared__ int s[256];
    int t = threadIdx.x;
    int i = blockIdx.x * 256 + t;
    int v = (i < N) ? cnt[i] : 0;
    s[t] = v;
    __syncthreads();
    for (int off = 1; off < 256; off <<= 1) {
        int u = (t >= off) ? s[t - off] : 0;
        __syncthreads();
        s[t] += u;
        __syncthreads();
    }
    if (i < N) {
        rowptr[i] = bsum[blockIdx.x] + s[t] - v;  // exclusive
        cnt[i] = 0;                               // reset for scatter fill
    }
}

// --- Kernel 4: scatter edges into CSR order, fusing normalized weight ---
__global__ void scatter_kernel(const int* __restrict__ row,
                               const int* __restrict__ col,
                               const float* __restrict__ ew,
                               const float* __restrict__ dis,
                               const int* __restrict__ rowptr,
                               int* __restrict__ fill,
                               float2* __restrict__ ewc, int E) {
    int e = blockIdx.x * blockDim.x + threadIdx.x;
    if (e < E) {
        int r = row[e];
        int c = col[e];
        float wv = -dis[r] * ew[e] * dis[c];
        int pos = rowptr[r] + atomicAdd(&fill[r], 1);
        ewc[pos] = make_float2(wv, __int_as_float(c));
    }
}

// --- Kernel 5: atomic-free CSR SpMM: one wave per row, lane = channel ---
// Coalesced 64-edge batch load + v_readlane broadcast of (w, col).
__global__ __launch_bounds__(256) void spmm_csr_kernel(
        const int* __restrict__ rowptr,
        const float2* __restrict__ ewc,
        const float* __restrict__ h,
        float* __restrict__ out, int N) {
    int wid = (blockIdx.x * blockDim.x + threadIdx.x) >> 6;  // row id
    int lane = threadIdx.x & 63;
    if (wid >= N) return;
    int beg = rowptr[wid];
    int end = rowptr[wid + 1];
    float acc = 0.0f;
    for (int base = beg; base < end; base += 64) {
        int idx = base + lane;
        float2 ed = (idx < end) ? ewc[idx] : make_float2(0.0f, 0.0f);
        int cnt = end - base; if (cnt > 64) cnt = 64;
        int j = 0;
        for (; j + 1 < cnt; j += 2) {
            float w0 = __int_as_float(__builtin_amdgcn_readlane(__float_as_int(ed.x), j));
            int   c0 = __builtin_amdgcn_readlane(__float_as_int(ed.y), j);
            float w1 = __int_as_float(__builtin_amdgcn_readlane(__float_as_int(ed.x), j + 1));
            int   c1 = __builtin_amdgcn_readlane(__float_as_int(ed.y), j + 1);
            float h0 = h[(size_t)c0 * C + lane];
            float h1 = h[(size_t)c1 * C + lane];
            acc = fmaf(w0, h0, acc);
            acc = fmaf(w1, h1, acc);
        }
        if (j < cnt) {
            float w0 = __int_as_float(__builtin_amdgcn_readlane(__float_as_int(ed.x), j));
            int   c0 = __builtin_amdgcn_readlane(__float_as_int(ed.y), j);
            acc = fmaf(w0, h[(size_t)c0 * C + lane], acc);
        }
    }
    out[(size_t)wid * C + lane] = acc;
}

// --- Kernel 6: fused dense epilogue as register-tiled GEMM ---
// out = relu([x | T1 | 2P-x] @ Wcat + b), Wcat = [192][64] (W row-major)
__global__ __launch_bounds__(256) void final_gemm_kernel(
        const float* __restrict__ x,
        const float* __restrict__ T1,
        const float* __restrict__ P,
        const float* __restrict__ W,   // [192][64] row-major
        const float* __restrict__ b,
        float* __restrict__ out, int N) {
    __shared__ float As[16][64];  // [k][node]
    __shared__ float Ws[16][64];  // [k][col]

    int t  = threadIdx.x;
    int tx = t & 15;         // col group: cols tx*4..+3
    int ty = t >> 4;         // row group: nodes ty*4..+3
    int n0 = blockIdx.x * 64;

    int sn = t >> 2;          // node 0..63
    int skb = (t & 3) * 4;    // k offset within slice

    float acc[4][4];
#pragma unroll
    for (int i = 0; i < 4; i++)
#pragma unroll
        for (int j = 0; j < 4; j++) acc[i][j] = 0.0f;

#pragma unroll 1
    for (int s = 0; s < 12; s++) {
        float4 wv = *(const float4*)(W + s * 1024 + t * 4);
        int nn = n0 + sn;
        float4 av = make_float4(0.f, 0.f, 0.f, 0.f);
        if (nn < N) {
            if (s < 4) {
                av = *(const float4*)(x + (size_t)nn * C + s * 16 + skb);
            } else if (s < 8) {
                av = *(const float4*)(T1 + (size_t)nn * C + (s - 4) * 16 + skb);
            } else {
                float4 pv = *(const float4*)(P + (size_t)nn * C + (s - 8) * 16 + skb);
                float4 xv = *(const float4*)(x + (size_t)nn * C + (s - 8) * 16 + skb);
                av = make_float4(2.0f * pv.x - xv.x, 2.0f * pv.y - xv.y,
                                 2.0f * pv.z - xv.z, 2.0f * pv.w - xv.w);
            }
        }
        __syncthreads();
        {
            int wk = (t * 4) >> 6;
            int wc = (t * 4) & 63;
            *(float4*)&Ws[wk][wc] = wv;
        }
        As[skb + 0][sn] = av.x;
        As[skb + 1][sn] = av.y;
        As[skb + 2][sn] = av.z;
        As[skb + 3][sn] = av.w;
        __syncthreads();

#pragma unroll
        for (int kk = 0; kk < 16; kk++) {
            float4 a4 = *(const float4*)&As[kk][ty * 4];
            float4 w4 = *(const float4*)&Ws[kk][tx * 4];
            float ar[4] = {a4.x, a4.y, a4.z, a4.w};
            float wr[4] = {w4.x, w4.y, w4.z, w4.w};
#pragma unroll
            for (int i = 0; i < 4; i++)
#pragma unroll
                for (int j = 0; j < 4; j++)
                    acc[i][j] = fmaf(ar[i], wr[j], acc[i][j]);
        }
    }

    float4 bv = *(const float4*)(b + tx * 4);
    float br[4] = {bv.x, bv.y, bv.z, bv.w};
#pragma unroll
    for (int i = 0; i < 4; i++) {
        int node = n0 + ty * 4 + i;
        if (node < N) {
            float4 o;
            o.x = fmaxf(acc[i][0] + br[0], 0.0f);
            o.y = fmaxf(acc[i][1] + br[1], 0.0f);
            o.z = fmaxf(acc[i][2] + br[2], 0.0f);
            o.w = fmaxf(acc[i][3] + br[3], 0.0f);
            *(float4*)(out + (size_t)node * C + tx * 4) = o;
        }
    }
}

extern "C" void kernel_launch(void* const* d_in, const int* in_sizes, int n_in,
                              void* d_out, int out_size, void* d_ws, size_t ws_size,
                              hipStream_t stream) {
    const float* x  = (const float*)d_in[0];
    const int*   ei = (const int*)d_in[1];
    const float* ew = (const float*)d_in[2];
    const float* W  = (const float*)d_in[3];
    const float* b  = (const float*)d_in[4];
    float* out = (float*)d_out;

    const int N = in_sizes[0] / C;
    const int E = in_sizes[2];
    const int* row = ei;        // edge_index[0]
    const int* col = ei + E;    // edge_index[1]

    char* ws = (char*)d_ws;
    size_t off = 0;
    auto alloc = [&](size_t bytes) {
        void* p = ws + off;
        off = (off + bytes + 255) & ~(size_t)255;
        return p;
    };
    float*  dis    = (float*)alloc((size_t)N * 4);
    int*    cnt    = (int*)alloc((size_t)N * 4);
    int*    rowptr = (int*)alloc((size_t)(N + 1) * 4);
    float2* ewc    = (float2*)alloc((size_t)E * 8);
    float*  T1     = (float*)alloc((size_t)N * C * 4);
    float*  P      = (float*)alloc((size_t)N * C * 4);
    int*    bsum   = (int*)alloc((size_t)256 * 4);

    hipMemsetAsync(dis, 0, (size_t)N * 4, stream);
    hipMemsetAsync(cnt, 0, (size_t)N * 4, stream);

    const int B = 256;
    const int G = (N + B - 1) / B;  // 196 <= 256

    deg_hist_kernel<<<(E + B - 1) / B, B, 0, stream>>>(row, ew, dis, cnt, E);
    dis_kernel<<<G, B, 0, stream>>>(dis, N);

    scanA_kernel<<<G, B, 0, stream>>>(cnt, bsum, N);
    scanB_kernel<<<1, B, 0, stream>>>(bsum, rowptr, G, N);
    scanC_kernel<<<G, B, 0, stream>>>(cnt, bsum, rowptr, N);

    scatter_kernel<<<(E + B - 1) / B, B, 0, stream>>>(row, col, ew, dis, rowptr,
                                                      cnt, ewc, E);

    int spmm_blocks = (int)(((long long)N * 64 + B - 1) / B);
    spmm_csr_kernel<<<spmm_blocks, B, 0, stream>>>(rowptr, ewc, x, T1, N);
    spmm_csr_kernel<<<spmm_blocks, B, 0, stream>>>(rowptr, ewc, T1, P, N);

    final_gemm_kernel<<<(N + 63) / 64, B, 0, stream>>>(x, T1, P, W, b, out, N);
}

// Round 4
// 288.462 us; speedup vs baseline: 2.2564x; 1.0231x over previous
//
#include <hip/hip_runtime.h>
#include <hip/hip_bf16.h>

#define C 64   // C_IN == C_OUT == 64
#define NCOPY 8

// --- Kernel 1: privatized degree + count histogram (copy = blockIdx & 7) ---
__global__ __launch_bounds__(256) void hist8_kernel(const int* __restrict__ row,
                                                    const float* __restrict__ ew,
                                                    float* __restrict__ deg8,
                                                    int* __restrict__ cnt8,
                                                    int E, int N) {
    int e = blockIdx.x * 256 + threadIdx.x;
    int copy = blockIdx.x & (NCOPY - 1);
    if (e < E) {
        int r = row[e];
        atomicAdd(&deg8[(size_t)copy * N + r], ew[e]);
        atomicAdd(&cnt8[(size_t)copy * N + r], 1);
    }
}

// --- Scan phase A: reduce 8 copies -> cnt, dis; per-block sums of cnt ---
__global__ __launch_bounds__(256) void scanA_kernel(const int* __restrict__ cnt8,
                                                    const float* __restrict__ deg8,
                                                    int* __restrict__ cnt,
                                                    float* __restrict__ dis,
                                                    int* __restrict__ bsum, int N) {
    __shared__ int s[256];
    int t = threadIdx.x;
    int i = blockIdx.x * 256 + t;
    int cv = 0;
    float dv = 0.0f;
    if (i < N) {
#pragma unroll
        for (int c = 0; c < NCOPY; c++) {
            cv += cnt8[(size_t)c * N + i];
            dv += deg8[(size_t)c * N + i];
        }
        cnt[i] = cv;
        dis[i] = (dv > 0.0f) ? rsqrtf(dv) : 0.0f;
    }
    s[t] = cv;
    __syncthreads();
    for (int off = 128; off > 0; off >>= 1) {
        if (t < off) s[t] += s[t + off];
        __syncthreads();
    }
    if (t == 0) bsum[blockIdx.x] = s[0];
}

// --- Scan phase B: exclusive scan of G (<=256) block sums; writes rowptr[N] ---
__global__ __launch_bounds__(256) void scanB_kernel(int* __restrict__ bsum,
                                                    int* __restrict__ rowptr,
                                                    int G, int N) {
    __shared__ int s[256];
    int t = threadIdx.x;
    int v = (t < G) ? bsum[t] : 0;
    s[t] = v;
    __syncthreads();
    for (int off = 1; off < 256; off <<= 1) {
        int u = (t >= off) ? s[t - off] : 0;
        __syncthreads();
        s[t] += u;
        __syncthreads();
    }
    if (t < G) bsum[t] = s[t] - v;          // exclusive block prefix
    if (t == 255) rowptr[N] = s[255];       // total edge count
}

// --- Scan phase C: rowptr + convert cnt8 into per-copy position counters ---
__global__ __launch_bounds__(256) void scanC_kernel(const int* __restrict__ cnt,
                                                    int* __restrict__ cnt8,
                                                    const int* __restrict__ bsum,
                                                    int* __restrict__ rowptr, int N) {
    __shared__ int s[256];
    int t = threadIdx.x;
    int i = blockIdx.x * 256 + t;
    int v = (i < N) ? cnt[i] : 0;
    s[t] = v;
    __syncthreads();
    for (int off = 1; off < 256; off <<= 1) {
        int u = (t >= off) ? s[t - off] : 0;
        __syncthreads();
        s[t] += u;
        __syncthreads();
    }
    if (i < N) {
        int rp = bsum[blockIdx.x] + s[t] - v;  // exclusive prefix
        rowptr[i] = rp;
        int run = rp;
#pragma unroll
        for (int c = 0; c < NCOPY; c++) {
            int tmp = cnt8[(size_t)c * N + i];
            cnt8[(size_t)c * N + i] = run;     // start slot for this copy
            run += tmp;
        }
    }
}

// --- Kernel 4: scatter edges into CSR via privatized position counters ---
__global__ __launch_bounds__(256) void scatter_kernel(const int* __restrict__ row,
                                                      const int* __restrict__ col,
                                                      const float* __restrict__ ew,
                                                      const float* __restrict__ dis,
                                                      int* __restrict__ cnt8,
                                                      float2* __restrict__ ewc,
                                                      int E, int N) {
    int e = blockIdx.x * 256 + threadIdx.x;
    int copy = blockIdx.x & (NCOPY - 1);
    if (e < E) {
        int r = row[e];
        int c = col[e];
        float wv = -dis[r] * ew[e] * dis[c];
        int pos = atomicAdd(&cnt8[(size_t)copy * N + r], 1);
        ewc[pos] = make_float2(wv, __int_as_float(c));
    }
}

// --- Kernel 5: atomic-free CSR SpMM: one wave per row, lane = channel ---
__global__ __launch_bounds__(256) void spmm_csr_kernel(
        const int* __restrict__ rowptr,
        const float2* __restrict__ ewc,
        const float* __restrict__ h,
        float* __restrict__ out, int N) {
    int wid = (blockIdx.x * blockDim.x + threadIdx.x) >> 6;  // row id
    int lane = threadIdx.x & 63;
    if (wid >= N) return;
    int beg = rowptr[wid];
    int end = rowptr[wid + 1];
    float acc = 0.0f;
    for (int base = beg; base < end; base += 64) {
        int idx = base + lane;
        float2 ed = (idx < end) ? ewc[idx] : make_float2(0.0f, 0.0f);
        int cnt = end - base; if (cnt > 64) cnt = 64;
        int j = 0;
        for (; j + 1 < cnt; j += 2) {
            float w0 = __int_as_float(__builtin_amdgcn_readlane(__float_as_int(ed.x), j));
            int   c0 = __builtin_amdgcn_readlane(__float_as_int(ed.y), j);
            float w1 = __int_as_float(__builtin_amdgcn_readlane(__float_as_int(ed.x), j + 1));
            int   c1 = __builtin_amdgcn_readlane(__float_as_int(ed.y), j + 1);
            float h0 = h[(size_t)c0 * C + lane];
            float h1 = h[(size_t)c1 * C + lane];
            acc = fmaf(w0, h0, acc);
            acc = fmaf(w1, h1, acc);
        }
        if (j < cnt) {
            float w0 = __int_as_float(__builtin_amdgcn_readlane(__float_as_int(ed.x), j));
            int   c0 = __builtin_amdgcn_readlane(__float_as_int(ed.y), j);
            acc = fmaf(w0, h[(size_t)c0 * C + lane], acc);
        }
    }
    out[(size_t)wid * C + lane] = acc;
}

// --- Kernel 6: fused dense epilogue as register-tiled GEMM ---
// out = relu([x | T1 | 2P-x] @ Wcat + b), Wcat = [192][64] (W row-major)
__global__ __launch_bounds__(256) void final_gemm_kernel(
        const float* __restrict__ x,
        const float* __restrict__ T1,
        const float* __restrict__ P,
        const float* __restrict__ W,   // [192][64] row-major
        const float* __restrict__ b,
        float* __restrict__ out, int N) {
    __shared__ float As[16][64];  // [k][node]
    __shared__ float Ws[16][64];  // [k][col]

    int t  = threadIdx.x;
    int tx = t & 15;
    int ty = t >> 4;
    int n0 = blockIdx.x * 64;

    int sn = t >> 2;
    int skb = (t & 3) * 4;

    float acc[4][4];
#pragma unroll
    for (int i = 0; i < 4; i++)
#pragma unroll
        for (int j = 0; j < 4; j++) acc[i][j] = 0.0f;

#pragma unroll 1
    for (int s = 0; s < 12; s++) {
        float4 wv = *(const float4*)(W + s * 1024 + t * 4);
        int nn = n0 + sn;
        float4 av = make_float4(0.f, 0.f, 0.f, 0.f);
        if (nn < N) {
            if (s < 4) {
                av = *(const float4*)(x + (size_t)nn * C + s * 16 + skb);
            } else if (s < 8) {
                av = *(const float4*)(T1 + (size_t)nn * C + (s - 4) * 16 + skb);
            } else {
                float4 pv = *(const float4*)(P + (size_t)nn * C + (s - 8) * 16 + skb);
                float4 xv = *(const float4*)(x + (size_t)nn * C + (s - 8) * 16 + skb);
                av = make_float4(2.0f * pv.x - xv.x, 2.0f * pv.y - xv.y,
                                 2.0f * pv.z - xv.z, 2.0f * pv.w - xv.w);
            }
        }
        __syncthreads();
        {
            int wk = (t * 4) >> 6;
            int wc = (t * 4) & 63;
            *(float4*)&Ws[wk][wc] = wv;
        }
        As[skb + 0][sn] = av.x;
        As[skb + 1][sn] = av.y;
        As[skb + 2][sn] = av.z;
        As[skb + 3][sn] = av.w;
        __syncthreads();

#pragma unroll
        for (int kk = 0; kk < 16; kk++) {
            float4 a4 = *(const float4*)&As[kk][ty * 4];
            float4 w4 = *(const float4*)&Ws[kk][tx * 4];
            float ar[4] = {a4.x, a4.y, a4.z, a4.w};
            float wr[4] = {w4.x, w4.y, w4.z, w4.w};
#pragma unroll
            for (int i = 0; i < 4; i++)
#pragma unroll
                for (int j = 0; j < 4; j++)
                    acc[i][j] = fmaf(ar[i], wr[j], acc[i][j]);
        }
    }

    float4 bv = *(const float4*)(b + tx * 4);
    float br[4] = {bv.x, bv.y, bv.z, bv.w};
#pragma unroll
    for (int i = 0; i < 4; i++) {
        int node = n0 + ty * 4 + i;
        if (node < N) {
            float4 o;
            o.x = fmaxf(acc[i][0] + br[0], 0.0f);
            o.y = fmaxf(acc[i][1] + br[1], 0.0f);
            o.z = fmaxf(acc[i][2] + br[2], 0.0f);
            o.w = fmaxf(acc[i][3] + br[3], 0.0f);
            *(float4*)(out + (size_t)node * C + tx * 4) = o;
        }
    }
}

extern "C" void kernel_launch(void* const* d_in, const int* in_sizes, int n_in,
                              void* d_out, int out_size, void* d_ws, size_t ws_size,
                              hipStream_t stream) {
    const float* x  = (const float*)d_in[0];
    const int*   ei = (const int*)d_in[1];
    const float* ew = (const float*)d_in[2];
    const float* W  = (const float*)d_in[3];
    const float* b  = (const float*)d_in[4];
    float* out = (float*)d_out;

    const int N = in_sizes[0] / C;
    const int E = in_sizes[2];
    const int* row = ei;        // edge_index[0]
    const int* col = ei + E;    // edge_index[1]

    char* ws = (char*)d_ws;
    size_t off = 0;
    auto alloc = [&](size_t bytes) {
        void* p = ws + off;
        off = (off + bytes + 255) & ~(size_t)255;
        return p;
    };
    float*  dis    = (float*)alloc((size_t)N * 4);
    int*    cnt    = (int*)alloc((size_t)N * 4);
    int*    rowptr = (int*)alloc((size_t)(N + 1) * 4);
    float2* ewc    = (float2*)alloc((size_t)E * 8);
    float*  T1     = (float*)alloc((size_t)N * C * 4);
    float*  P      = (float*)alloc((size_t)N * C * 4);
    int*    bsum   = (int*)alloc((size_t)256 * 4);
    int*    cnt8   = (int*)alloc((size_t)NCOPY * N * 4);
    float*  deg8   = (float*)alloc((size_t)NCOPY * N * 4);

    hipMemsetAsync(cnt8, 0, (size_t)NCOPY * N * 4, stream);
    hipMemsetAsync(deg8, 0, (size_t)NCOPY * N * 4, stream);

    const int B = 256;
    const int G = (N + B - 1) / B;  // 196 <= 256

    hist8_kernel<<<(E + B - 1) / B, B, 0, stream>>>(row, ew, deg8, cnt8, E, N);
    scanA_kernel<<<G, B, 0, stream>>>(cnt8, deg8, cnt, dis, bsum, N);
    scanB_kernel<<<1, B, 0, stream>>>(bsum, rowptr, G, N);
    scanC_kernel<<<G, B, 0, stream>>>(cnt, cnt8, bsum, rowptr, N);
    scatter_kernel<<<(E + B - 1) / B, B, 0, stream>>>(row, col, ew, dis, cnt8,
                                                      ewc, E, N);

    int spmm_blocks = (int)(((long long)N * 64 + B - 1) / B);
    spmm_csr_kernel<<<spmm_blocks, B, 0, stream>>>(rowptr, ewc, x, T1, N);
    spmm_csr_kernel<<<spmm_blocks, B, 0, stream>>>(rowptr, ewc, T1, P, N);

    final_gemm_kernel<<<(N + 63) / 64, B, 0, stream>>>(x, T1, P, W, b, out, N);
}

// Round 5
// 229.799 us; speedup vs baseline: 2.8324x; 1.2553x over previous
//
#include <hip/hip_runtime.h>
#include <hip/hip_bf16.h>

#define C 64   // C_IN == C_OUT == 64
#define NCOPY 8
#define FXSCALE 16777216.0f            // 2^24
#define LOW44 ((1ULL << 44) - 1)

// --- Kernel 1: fused histogram. One u64 atomic per edge:
//     bits [44:63] = count, bits [0:43] = fixed-point (2^-24) sum of ew.
//     Return value's high bits = this edge's rank within (copy,row).
__global__ __launch_bounds__(256) void hist8_kernel(const int* __restrict__ row,
                                                    const float* __restrict__ ew,
                                                    unsigned long long* __restrict__ cd8,
                                                    int* __restrict__ rank,
                                                    int E, int N) {
    int e = blockIdx.x * 256 + threadIdx.x;
    int copy = blockIdx.x & (NCOPY - 1);
    if (e < E) {
        int r = row[e];
        unsigned long long fx = (unsigned long long)__float2uint_rn(ew[e] * FXSCALE);
        unsigned long long inc = (1ULL << 44) | fx;
        unsigned long long old = atomicAdd(&cd8[(size_t)copy * N + r], inc);
        rank[e] = (int)(old >> 44);
    }
}

// --- Scan phase A: reduce 8 copies -> cnt, dis; per-block sums of cnt ---
__global__ __launch_bounds__(256) void scanA_kernel(const unsigned long long* __restrict__ cd8,
                                                    int* __restrict__ cnt,
                                                    float* __restrict__ dis,
                                                    int* __restrict__ bsum, int N) {
    __shared__ int s[256];
    int t = threadIdx.x;
    int i = blockIdx.x * 256 + t;
    int cv = 0;
    unsigned long long dfx = 0;
    if (i < N) {
#pragma unroll
        for (int c = 0; c < NCOPY; c++) {
            unsigned long long v = cd8[(size_t)c * N + i];
            cv += (int)(v >> 44);
            dfx += (v & LOW44);
        }
        cnt[i] = cv;
        float dv = (float)dfx * (1.0f / FXSCALE);
        dis[i] = (dv > 0.0f) ? rsqrtf(dv) : 0.0f;
    }
    s[t] = cv;
    __syncthreads();
    for (int off = 128; off > 0; off >>= 1) {
        if (t < off) s[t] += s[t + off];
        __syncthreads();
    }
    if (t == 0) bsum[blockIdx.x] = s[0];
}

// --- Scan phase B: exclusive scan of G (<=256) block sums; writes rowptr[N] ---
__global__ __launch_bounds__(256) void scanB_kernel(int* __restrict__ bsum,
                                                    int* __restrict__ rowptr,
                                                    int G, int N) {
    __shared__ int s[256];
    int t = threadIdx.x;
    int v = (t < G) ? bsum[t] : 0;
    s[t] = v;
    __syncthreads();
    for (int off = 1; off < 256; off <<= 1) {
        int u = (t >= off) ? s[t - off] : 0;
        __syncthreads();
        s[t] += u;
        __syncthreads();
    }
    if (t < G) bsum[t] = s[t] - v;          // exclusive block prefix
    if (t == 255) rowptr[N] = s[255];       // total edge count
}

// --- Scan phase C: rowptr + per-copy start slots (atomic-free scatter prep) ---
__global__ __launch_bounds__(256) void scanC_kernel(const int* __restrict__ cnt,
                                                    const unsigned long long* __restrict__ cd8,
                                                    int* __restrict__ start8,
                                                    const int* __restrict__ bsum,
                                                    int* __restrict__ rowptr, int N) {
    __shared__ int s[256];
    int t = threadIdx.x;
    int i = blockIdx.x * 256 + t;
    int v = (i < N) ? cnt[i] : 0;
    s[t] = v;
    __syncthreads();
    for (int off = 1; off < 256; off <<= 1) {
        int u = (t >= off) ? s[t - off] : 0;
        __syncthreads();
        s[t] += u;
        __syncthreads();
    }
    if (i < N) {
        int rp = bsum[blockIdx.x] + s[t] - v;  // exclusive prefix
        rowptr[i] = rp;
        int run = rp;
#pragma unroll
        for (int c = 0; c < NCOPY; c++) {
            int tmp = (int)(cd8[(size_t)c * N + i] >> 44);
            start8[(size_t)c * N + i] = run;   // start slot for this copy
            run += tmp;
        }
    }
}

// --- Kernel 4: atomic-free scatter: pos = start8[copy][r] + rank[e] ---
__global__ __launch_bounds__(256) void scatter_kernel(const int* __restrict__ row,
                                                      const int* __restrict__ col,
                                                      const float* __restrict__ ew,
                                                      const float* __restrict__ dis,
                                                      const int* __restrict__ start8,
                                                      const int* __restrict__ rank,
                                                      float2* __restrict__ ewc,
                                                      int E, int N) {
    int e = blockIdx.x * 256 + threadIdx.x;
    int copy = blockIdx.x & (NCOPY - 1);
    if (e < E) {
        int r = row[e];
        int c = col[e];
        float wv = -dis[r] * ew[e] * dis[c];
        int pos = start8[(size_t)copy * N + r] + rank[e];
        ewc[pos] = make_float2(wv, __int_as_float(c));
    }
}

// --- Kernel 5: atomic-free CSR SpMM: one wave per row, lane = channel ---
__global__ __launch_bounds__(256) void spmm_csr_kernel(
        const int* __restrict__ rowptr,
        const float2* __restrict__ ewc,
        const float* __restrict__ h,
        float* __restrict__ out, int N) {
    int wid = (blockIdx.x * blockDim.x + threadIdx.x) >> 6;  // row id
    int lane = threadIdx.x & 63;
    if (wid >= N) return;
    int beg = rowptr[wid];
    int end = rowptr[wid + 1];
    float acc = 0.0f;
    for (int base = beg; base < end; base += 64) {
        int idx = base + lane;
        float2 ed = (idx < end) ? ewc[idx] : make_float2(0.0f, 0.0f);
        int cnt = end - base; if (cnt > 64) cnt = 64;
        int j = 0;
        for (; j + 1 < cnt; j += 2) {
            float w0 = __int_as_float(__builtin_amdgcn_readlane(__float_as_int(ed.x), j));
            int   c0 = __builtin_amdgcn_readlane(__float_as_int(ed.y), j);
            float w1 = __int_as_float(__builtin_amdgcn_readlane(__float_as_int(ed.x), j + 1));
            int   c1 = __builtin_amdgcn_readlane(__float_as_int(ed.y), j + 1);
            float h0 = h[(size_t)c0 * C + lane];
            float h1 = h[(size_t)c1 * C + lane];
            acc = fmaf(w0, h0, acc);
            acc = fmaf(w1, h1, acc);
        }
        if (j < cnt) {
            float w0 = __int_as_float(__builtin_amdgcn_readlane(__float_as_int(ed.x), j));
            int   c0 = __builtin_amdgcn_readlane(__float_as_int(ed.y), j);
            acc = fmaf(w0, h[(size_t)c0 * C + lane], acc);
        }
    }
    out[(size_t)wid * C + lane] = acc;
}

// --- Kernel 6: fused dense epilogue as register-tiled GEMM ---
// out = relu([x | T1 | 2P-x] @ Wcat + b), Wcat = [192][64] (W row-major)
__global__ __launch_bounds__(256) void final_gemm_kernel(
        const float* __restrict__ x,
        const float* __restrict__ T1,
        const float* __restrict__ P,
        const float* __restrict__ W,   // [192][64] row-major
        const float* __restrict__ b,
        float* __restrict__ out, int N) {
    __shared__ float As[16][64];  // [k][node]
    __shared__ float Ws[16][64];  // [k][col]

    int t  = threadIdx.x;
    int tx = t & 15;
    int ty = t >> 4;
    int n0 = blockIdx.x * 64;

    int sn = t >> 2;
    int skb = (t & 3) * 4;

    float acc[4][4];
#pragma unroll
    for (int i = 0; i < 4; i++)
#pragma unroll
        for (int j = 0; j < 4; j++) acc[i][j] = 0.0f;

#pragma unroll 1
    for (int s = 0; s < 12; s++) {
        float4 wv = *(const float4*)(W + s * 1024 + t * 4);
        int nn = n0 + sn;
        float4 av = make_float4(0.f, 0.f, 0.f, 0.f);
        if (nn < N) {
            if (s < 4) {
                av = *(const float4*)(x + (size_t)nn * C + s * 16 + skb);
            } else if (s < 8) {
                av = *(const float4*)(T1 + (size_t)nn * C + (s - 4) * 16 + skb);
            } else {
                float4 pv = *(const float4*)(P + (size_t)nn * C + (s - 8) * 16 + skb);
                float4 xv = *(const float4*)(x + (size_t)nn * C + (s - 8) * 16 + skb);
                av = make_float4(2.0f * pv.x - xv.x, 2.0f * pv.y - xv.y,
                                 2.0f * pv.z - xv.z, 2.0f * pv.w - xv.w);
            }
        }
        __syncthreads();
        {
            int wk = (t * 4) >> 6;
            int wc = (t * 4) & 63;
            *(float4*)&Ws[wk][wc] = wv;
        }
        As[skb + 0][sn] = av.x;
        As[skb + 1][sn] = av.y;
        As[skb + 2][sn] = av.z;
        As[skb + 3][sn] = av.w;
        __syncthreads();

#pragma unroll
        for (int kk = 0; kk < 16; kk++) {
            float4 a4 = *(const float4*)&As[kk][ty * 4];
            float4 w4 = *(const float4*)&Ws[kk][tx * 4];
            float ar[4] = {a4.x, a4.y, a4.z, a4.w};
            float wr[4] = {w4.x, w4.y, w4.z, w4.w};
#pragma unroll
            for (int i = 0; i < 4; i++)
#pragma unroll
                for (int j = 0; j < 4; j++)
                    acc[i][j] = fmaf(ar[i], wr[j], acc[i][j]);
        }
    }

    float4 bv = *(const float4*)(b + tx * 4);
    float br[4] = {bv.x, bv.y, bv.z, bv.w};
#pragma unroll
    for (int i = 0; i < 4; i++) {
        int node = n0 + ty * 4 + i;
        if (node < N) {
            float4 o;
            o.x = fmaxf(acc[i][0] + br[0], 0.0f);
            o.y = fmaxf(acc[i][1] + br[1], 0.0f);
            o.z = fmaxf(acc[i][2] + br[2], 0.0f);
            o.w = fmaxf(acc[i][3] + br[3], 0.0f);
            *(float4*)(out + (size_t)node * C + tx * 4) = o;
        }
    }
}

extern "C" void kernel_launch(void* const* d_in, const int* in_sizes, int n_in,
                              void* d_out, int out_size, void* d_ws, size_t ws_size,
                              hipStream_t stream) {
    const float* x  = (const float*)d_in[0];
    const int*   ei = (const int*)d_in[1];
    const float* ew = (const float*)d_in[2];
    const float* W  = (const float*)d_in[3];
    const float* b  = (const float*)d_in[4];
    float* out = (float*)d_out;

    const int N = in_sizes[0] / C;
    const int E = in_sizes[2];
    const int* row = ei;        // edge_index[0]
    const int* col = ei + E;    // edge_index[1]

    char* ws = (char*)d_ws;
    size_t off = 0;
    auto alloc = [&](size_t bytes) {
        void* p = ws + off;
        off = (off + bytes + 255) & ~(size_t)255;
        return p;
    };
    float*  dis    = (float*)alloc((size_t)N * 4);
    int*    cnt    = (int*)alloc((size_t)N * 4);
    int*    rowptr = (int*)alloc((size_t)(N + 1) * 4);
    float2* ewc    = (float2*)alloc((size_t)E * 8);
    float*  T1     = (float*)alloc((size_t)N * C * 4);
    float*  P      = (float*)alloc((size_t)N * C * 4);
    int*    bsum   = (int*)alloc((size_t)256 * 4);
    unsigned long long* cd8 = (unsigned long long*)alloc((size_t)NCOPY * N * 8);
    int*    start8 = (int*)alloc((size_t)NCOPY * N * 4);
    int*    rank   = (int*)alloc((size_t)E * 4);

    hipMemsetAsync(cd8, 0, (size_t)NCOPY * N * 8, stream);

    const int B = 256;
    const int G = (N + B - 1) / B;  // 196 <= 256

    hist8_kernel<<<(E + B - 1) / B, B, 0, stream>>>(row, ew, cd8, rank, E, N);
    scanA_kernel<<<G, B, 0, stream>>>(cd8, cnt, dis, bsum, N);
    scanB_kernel<<<1, B, 0, stream>>>(bsum, rowptr, G, N);
    scanC_kernel<<<G, B, 0, stream>>>(cnt, cd8, start8, bsum, rowptr, N);
    scatter_kernel<<<(E + B - 1) / B, B, 0, stream>>>(row, col, ew, dis, start8,
                                                      rank, ewc, E, N);

    int spmm_blocks = (int)(((long long)N * 64 + B - 1) / B);
    spmm_csr_kernel<<<spmm_blocks, B, 0, stream>>>(rowptr, ewc, x, T1, N);
    spmm_csr_kernel<<<spmm_blocks, B, 0, stream>>>(rowptr, ewc, T1, P, N);

    final_gemm_kernel<<<(N + 63) / 64, B, 0, stream>>>(x, T1, P, W, b, out, N);
}

// Round 6
// 213.848 us; speedup vs baseline: 3.0436x; 1.0746x over previous
//
#include <hip/hip_runtime.h>
#include <hip/hip_bf16.h>

#define C 64   // C_IN == C_OUT == 64
#define NCOPY 8
#define FXSCALE 16777216.0f            // 2^24
#define LOW44 ((1ULL << 44) - 1)

__device__ __forceinline__ unsigned short f2bf_rne(float v) {
    unsigned u = __float_as_uint(v);
    u += 0x7FFFu + ((u >> 16) & 1u);
    return (unsigned short)(u >> 16);
}
__device__ __forceinline__ float bf2f(unsigned short u) {
    return __uint_as_float((unsigned)u << 16);
}

// --- Kernel 1: fused histogram. One u64 atomic per edge:
//     bits [44:63] = count, bits [0:43] = fixed-point (2^-24) sum of ew.
//     Return value's high bits = this edge's rank within (copy,row).
__global__ __launch_bounds__(256) void hist8_kernel(const int* __restrict__ row,
                                                    const float* __restrict__ ew,
                                                    unsigned long long* __restrict__ cd8,
                                                    int* __restrict__ rank,
                                                    int E, int N) {
    int e = blockIdx.x * 256 + threadIdx.x;
    int copy = blockIdx.x & (NCOPY - 1);
    if (e < E) {
        int r = row[e];
        unsigned long long fx = (unsigned long long)__float2uint_rn(ew[e] * FXSCALE);
        unsigned long long inc = (1ULL << 44) | fx;
        unsigned long long old = atomicAdd(&cd8[(size_t)copy * N + r], inc);
        rank[e] = (int)(old >> 44);
    }
}

// --- x -> bf16 copy (gather operand for prop 1) ---
__global__ __launch_bounds__(256) void cvt_kernel(const float* __restrict__ x,
                                                  unsigned short* __restrict__ xh,
                                                  int total4) {
    int i = blockIdx.x * 256 + threadIdx.x;
    if (i < total4) {
        float4 v = *(const float4*)(x + (size_t)i * 4);
        ushort4 o;
        o.x = f2bf_rne(v.x); o.y = f2bf_rne(v.y);
        o.z = f2bf_rne(v.z); o.w = f2bf_rne(v.w);
        *(ushort4*)(xh + (size_t)i * 4) = o;
    }
}

// --- Scan phase A: reduce 8 copies -> cnt, dis; per-block sums of cnt ---
__global__ __launch_bounds__(256) void scanA_kernel(const unsigned long long* __restrict__ cd8,
                                                    int* __restrict__ cnt,
                                                    float* __restrict__ dis,
                                                    int* __restrict__ bsum, int N) {
    __shared__ int s[256];
    int t = threadIdx.x;
    int i = blockIdx.x * 256 + t;
    int cv = 0;
    unsigned long long dfx = 0;
    if (i < N) {
#pragma unroll
        for (int c = 0; c < NCOPY; c++) {
            unsigned long long v = cd8[(size_t)c * N + i];
            cv += (int)(v >> 44);
            dfx += (v & LOW44);
        }
        cnt[i] = cv;
        float dv = (float)dfx * (1.0f / FXSCALE);
        dis[i] = (dv > 0.0f) ? rsqrtf(dv) : 0.0f;
    }
    s[t] = cv;
    __syncthreads();
    for (int off = 128; off > 0; off >>= 1) {
        if (t < off) s[t] += s[t + off];
        __syncthreads();
    }
    if (t == 0) bsum[blockIdx.x] = s[0];
}

// --- Scan phase B: exclusive scan of G (<=256) block sums; writes rowptr[N] ---
__global__ __launch_bounds__(256) void scanB_kernel(int* __restrict__ bsum,
                                                    int* __restrict__ rowptr,
                                                    int G, int N) {
    __shared__ int s[256];
    int t = threadIdx.x;
    int v = (t < G) ? bsum[t] : 0;
    s[t] = v;
    __syncthreads();
    for (int off = 1; off < 256; off <<= 1) {
        int u = (t >= off) ? s[t - off] : 0;
        __syncthreads();
        s[t] += u;
        __syncthreads();
    }
    if (t < G) bsum[t] = s[t] - v;          // exclusive block prefix
    if (t == 255) rowptr[N] = s[255];       // total edge count
}

// --- Scan phase C: rowptr + per-copy start slots (atomic-free scatter prep) ---
__global__ __launch_bounds__(256) void scanC_kernel(const int* __restrict__ cnt,
                                                    const unsigned long long* __restrict__ cd8,
                                                    int* __restrict__ start8,
                                                    const int* __restrict__ bsum,
                                                    int* __restrict__ rowptr, int N) {
    __shared__ int s[256];
    int t = threadIdx.x;
    int i = blockIdx.x * 256 + t;
    int v = (i < N) ? cnt[i] : 0;
    s[t] = v;
    __syncthreads();
    for (int off = 1; off < 256; off <<= 1) {
        int u = (t >= off) ? s[t - off] : 0;
        __syncthreads();
        s[t] += u;
        __syncthreads();
    }
    if (i < N) {
        int rp = bsum[blockIdx.x] + s[t] - v;  // exclusive prefix
        rowptr[i] = rp;
        int run = rp;
#pragma unroll
        for (int c = 0; c < NCOPY; c++) {
            int tmp = (int)(cd8[(size_t)c * N + i] >> 44);
            start8[(size_t)c * N + i] = run;   // start slot for this copy
            run += tmp;
        }
    }
}

// --- Kernel 4: atomic-free scatter: pos = start8[copy][r] + rank[e] ---
__global__ __launch_bounds__(256) void scatter_kernel(const int* __restrict__ row,
                                                      const int* __restrict__ col,
                                                      const float* __restrict__ ew,
                                                      const float* __restrict__ dis,
                                                      const int* __restrict__ start8,
                                                      const int* __restrict__ rank,
                                                      float2* __restrict__ ewc,
                                                      int E, int N) {
    int e = blockIdx.x * 256 + threadIdx.x;
    int copy = blockIdx.x & (NCOPY - 1);
    if (e < E) {
        int r = row[e];
        int c = col[e];
        float wv = -dis[r] * ew[e] * dis[c];
        int pos = start8[(size_t)copy * N + r] + rank[e];
        ewc[pos] = make_float2(wv, __int_as_float(c));
    }
}

// --- Kernel 5: atomic-free CSR SpMM, bf16 gather operand, fp32 accum ---
// one wave per row, lane = channel; 4-way unrolled edge loop (4 loads in flight)
__global__ __launch_bounds__(256) void spmm_csr_kernel(
        const int* __restrict__ rowptr,
        const float2* __restrict__ ewc,
        const unsigned short* __restrict__ h,   // bf16 [N][C]
        float* __restrict__ out32,              // fp32 [N][C]
        unsigned short* __restrict__ outbf,     // bf16 [N][C]
        int N) {
    int wid = (blockIdx.x * blockDim.x + threadIdx.x) >> 6;  // row id
    int lane = threadIdx.x & 63;
    if (wid >= N) return;
    int beg = rowptr[wid];
    int end = rowptr[wid + 1];
    float a0 = 0.0f, a1 = 0.0f, a2 = 0.0f, a3 = 0.0f;
    for (int base = beg; base < end; base += 64) {
        int idx = base + lane;
        float2 ed = (idx < end) ? ewc[idx] : make_float2(0.0f, 0.0f);
        int cnt = end - base; if (cnt > 64) cnt = 64;
        int j = 0;
        for (; j + 3 < cnt; j += 4) {
            float w0 = __int_as_float(__builtin_amdgcn_readlane(__float_as_int(ed.x), j));
            int   c0 = __builtin_amdgcn_readlane(__float_as_int(ed.y), j);
            float w1 = __int_as_float(__builtin_amdgcn_readlane(__float_as_int(ed.x), j + 1));
            int   c1 = __builtin_amdgcn_readlane(__float_as_int(ed.y), j + 1);
            float w2 = __int_as_float(__builtin_amdgcn_readlane(__float_as_int(ed.x), j + 2));
            int   c2 = __builtin_amdgcn_readlane(__float_as_int(ed.y), j + 2);
            float w3 = __int_as_float(__builtin_amdgcn_readlane(__float_as_int(ed.x), j + 3));
            int   c3 = __builtin_amdgcn_readlane(__float_as_int(ed.y), j + 3);
            float h0 = bf2f(h[(size_t)c0 * C + lane]);
            float h1 = bf2f(h[(size_t)c1 * C + lane]);
            float h2 = bf2f(h[(size_t)c2 * C + lane]);
            float h3 = bf2f(h[(size_t)c3 * C + lane]);
            a0 = fmaf(w0, h0, a0);
            a1 = fmaf(w1, h1, a1);
            a2 = fmaf(w2, h2, a2);
            a3 = fmaf(w3, h3, a3);
        }
        for (; j < cnt; j++) {
            float w0 = __int_as_float(__builtin_amdgcn_readlane(__float_as_int(ed.x), j));
            int   c0 = __builtin_amdgcn_readlane(__float_as_int(ed.y), j);
            a0 = fmaf(w0, bf2f(h[(size_t)c0 * C + lane]), a0);
        }
    }
    float acc = (a0 + a1) + (a2 + a3);
    size_t o = (size_t)wid * C + lane;
    out32[o] = acc;
    outbf[o] = f2bf_rne(acc);
}

// --- Kernel 6: fused dense epilogue as register-tiled GEMM ---
// out = relu([x | T1 | 2P-x] @ Wcat + b), Wcat = [192][64] (W row-major)
__global__ __launch_bounds__(256) void final_gemm_kernel(
        const float* __restrict__ x,
        const float* __restrict__ T1,
        const float* __restrict__ P,
        const float* __restrict__ W,   // [192][64] row-major
        const float* __restrict__ b,
        float* __restrict__ out, int N) {
    __shared__ float As[16][64];  // [k][node]
    __shared__ float Ws[16][64];  // [k][col]

    int t  = threadIdx.x;
    int tx = t & 15;
    int ty = t >> 4;
    int n0 = blockIdx.x * 64;

    int sn = t >> 2;
    int skb = (t & 3) * 4;

    float acc[4][4];
#pragma unroll
    for (int i = 0; i < 4; i++)
#pragma unroll
        for (int j = 0; j < 4; j++) acc[i][j] = 0.0f;

#pragma unroll 1
    for (int s = 0; s < 12; s++) {
        float4 wv = *(const float4*)(W + s * 1024 + t * 4);
        int nn = n0 + sn;
        float4 av = make_float4(0.f, 0.f, 0.f, 0.f);
        if (nn < N) {
            if (s < 4) {
                av = *(const float4*)(x + (size_t)nn * C + s * 16 + skb);
            } else if (s < 8) {
                av = *(const float4*)(T1 + (size_t)nn * C + (s - 4) * 16 + skb);
            } else {
                float4 pv = *(const float4*)(P + (size_t)nn * C + (s - 8) * 16 + skb);
                float4 xv = *(const float4*)(x + (size_t)nn * C + (s - 8) * 16 + skb);
                av = make_float4(2.0f * pv.x - xv.x, 2.0f * pv.y - xv.y,
                                 2.0f * pv.z - xv.z, 2.0f * pv.w - xv.w);
            }
        }
        __syncthreads();
        {
            int wk = (t * 4) >> 6;
            int wc = (t * 4) & 63;
            *(float4*)&Ws[wk][wc] = wv;
        }
        As[skb + 0][sn] = av.x;
        As[skb + 1][sn] = av.y;
        As[skb + 2][sn] = av.z;
        As[skb + 3][sn] = av.w;
        __syncthreads();

#pragma unroll
        for (int kk = 0; kk < 16; kk++) {
            float4 a4 = *(const float4*)&As[kk][ty * 4];
            float4 w4 = *(const float4*)&Ws[kk][tx * 4];
            float ar[4] = {a4.x, a4.y, a4.z, a4.w};
            float wr[4] = {w4.x, w4.y, w4.z, w4.w};
#pragma unroll
            for (int i = 0; i < 4; i++)
#pragma unroll
                for (int j = 0; j < 4; j++)
                    acc[i][j] = fmaf(ar[i], wr[j], acc[i][j]);
        }
    }

    float4 bv = *(const float4*)(b + tx * 4);
    float br[4] = {bv.x, bv.y, bv.z, bv.w};
#pragma unroll
    for (int i = 0; i < 4; i++) {
        int node = n0 + ty * 4 + i;
        if (node < N) {
            float4 o;
            o.x = fmaxf(acc[i][0] + br[0], 0.0f);
            o.y = fmaxf(acc[i][1] + br[1], 0.0f);
            o.z = fmaxf(acc[i][2] + br[2], 0.0f);
            o.w = fmaxf(acc[i][3] + br[3], 0.0f);
            *(float4*)(out + (size_t)node * C + tx * 4) = o;
        }
    }
}

extern "C" void kernel_launch(void* const* d_in, const int* in_sizes, int n_in,
                              void* d_out, int out_size, void* d_ws, size_t ws_size,
                              hipStream_t stream) {
    const float* x  = (const float*)d_in[0];
    const int*   ei = (const int*)d_in[1];
    const float* ew = (const float*)d_in[2];
    const float* W  = (const float*)d_in[3];
    const float* b  = (const float*)d_in[4];
    float* out = (float*)d_out;

    const int N = in_sizes[0] / C;
    const int E = in_sizes[2];
    const int* row = ei;        // edge_index[0]
    const int* col = ei + E;    // edge_index[1]

    char* ws = (char*)d_ws;
    size_t off = 0;
    auto alloc = [&](size_t bytes) {
        void* p = ws + off;
        off = (off + bytes + 255) & ~(size_t)255;
        return p;
    };
    float*  dis    = (float*)alloc((size_t)N * 4);
    int*    cnt    = (int*)alloc((size_t)N * 4);
    int*    rowptr = (int*)alloc((size_t)(N + 1) * 4);
    float2* ewc    = (float2*)alloc((size_t)E * 8);
    float*  T1     = (float*)alloc((size_t)N * C * 4);
    float*  P      = (float*)alloc((size_t)N * C * 4);
    int*    bsum   = (int*)alloc((size_t)256 * 4);
    unsigned long long* cd8 = (unsigned long long*)alloc((size_t)NCOPY * N * 8);
    int*    start8 = (int*)alloc((size_t)NCOPY * N * 4);
    int*    rank   = (int*)alloc((size_t)E * 4);
    unsigned short* xh  = (unsigned short*)alloc((size_t)N * C * 2);
    unsigned short* T1h = (unsigned short*)alloc((size_t)N * C * 2);
    unsigned short* Ph  = (unsigned short*)alloc((size_t)N * C * 2);  // unused sink

    hipMemsetAsync(cd8, 0, (size_t)NCOPY * N * 8, stream);

    const int B = 256;
    const int G = (N + B - 1) / B;  // 196 <= 256

    hist8_kernel<<<(E + B - 1) / B, B, 0, stream>>>(row, ew, cd8, rank, E, N);
    int total4 = N * C / 4;
    cvt_kernel<<<(total4 + B - 1) / B, B, 0, stream>>>(x, xh, total4);
    scanA_kernel<<<G, B, 0, stream>>>(cd8, cnt, dis, bsum, N);
    scanB_kernel<<<1, B, 0, stream>>>(bsum, rowptr, G, N);
    scanC_kernel<<<G, B, 0, stream>>>(cnt, cd8, start8, bsum, rowptr, N);
    scatter_kernel<<<(E + B - 1) / B, B, 0, stream>>>(row, col, ew, dis, start8,
                                                      rank, ewc, E, N);

    int spmm_blocks = (int)(((long long)N * 64 + B - 1) / B);
    spmm_csr_kernel<<<spmm_blocks, B, 0, stream>>>(rowptr, ewc, xh, T1, T1h, N);
    spmm_csr_kernel<<<spmm_blocks, B, 0, stream>>>(rowptr, ewc, T1h, P, Ph, N);

    final_gemm_kernel<<<(N + 63) / 64, B, 0, stream>>>(x, T1, P, W, b, out, N);
}